// Round 5
// baseline (25.667 us; speedup 1.0000x reference)
//
#include <hip/hip_runtime.h>
#include <math.h>

#define HF 64
#define WF 64
#define CC 512
#define NROI 256
#define NBINS 21   // 1 + 4 + 16

__device__ __forceinline__ float4 max4(float4 a, float4 b) {
    float4 r;
    r.x = fmaxf(a.x, b.x); r.y = fmaxf(a.y, b.y);
    r.z = fmaxf(a.z, b.z); r.w = fmaxf(a.w, b.w);
    return r;
}

// Fused single kernel: block = (roi, channel-eighth of 64 ch), 256 threads.
// Wave w owns jy-strip w and computes its 4 jx fine bins (acc[4], unrolled
// indexing only). Lanes: cl = lane&15 -> 4 channels (float4), pp = lane>>4 ->
// pixel parity mod 4. p2/p1 derived block-locally via LDS (exact: max over
// identical operand sets; boundary arithmetic bitwise-identical to reference).
// XCD swizzle: bid&7 = eighth -> XCD; per-XCD image slice 64*64*64*4B = 1 MB < 4 MiB L2.
__global__ __launch_bounds__(256) void roi_pool_fused(
    const float* __restrict__ img,
    const float* __restrict__ rois,
    float* __restrict__ out)
{
    __shared__ float fineLds[4][4][64];   // [jy][jx][ch]
    __shared__ float p2Lds[2][2][64];     // [i2][j2][ch]

    const int bid  = blockIdx.x;          // [0, 2048)
    const int e    = bid & 7;             // channel eighth -> XCD
    const int roi  = bid >> 3;
    const int tid  = threadIdx.x;
    const int wv   = tid >> 6;            // wave id = jy strip
    const int lane = tid & 63;
    const int pp   = lane >> 4;           // pixel parity (mod 4)
    const int cl   = lane & 15;           // channel lane
    const int c0   = e * 64 + cl * 4;

    const float x = rois[roi * 4 + 0];
    const float y = rois[roi * 4 + 1];
    const float w = rois[roi * 4 + 2];
    const float h = rois[roi * 4 + 3];

    // Reference quirk: x-boundaries (W axis) use col_len = h/p; y-boundaries use w/p.
    const float clh = h * 0.25f;   // exact
    const float clw = w * 0.25f;   // exact

    int bx[5];
#pragma unroll
    for (int i = 0; i < 5; ++i)
        bx[i] = (int)rintf(__fadd_rn(x, __fmul_rn((float)i, clh)));

    const int y1 = (int)rintf(__fadd_rn(y, __fmul_rn((float)wv,       clw)));
    const int y2 = (int)rintf(__fadd_rn(y, __fmul_rn((float)(wv + 1), clw)));

    float4 acc[4];
#pragma unroll
    for (int jx = 0; jx < 4; ++jx) {
        acc[jx].x = -INFINITY; acc[jx].y = -INFINITY;
        acc[jx].z = -INFINITY; acc[jx].w = -INFINITY;
    }

    const float* base = img + c0;
    for (int hh = y1; hh < y2; ++hh) {
        const float* rowp = base + (size_t)hh * (WF * CC);
#pragma unroll
        for (int jx = 0; jx < 4; ++jx) {
            for (int ww = bx[jx] + pp; ww < bx[jx + 1]; ww += 4) {
                acc[jx] = max4(acc[jx], *(const float4*)(rowp + (size_t)ww * CC));
            }
        }
    }

    // combine the 4 pixel-parity groups (same channels, disjoint pixel sets)
#pragma unroll
    for (int jx = 0; jx < 4; ++jx) {
        float4 a = acc[jx];
        a.x = fmaxf(a.x, __shfl_xor(a.x, 16));
        a.y = fmaxf(a.y, __shfl_xor(a.y, 16));
        a.z = fmaxf(a.z, __shfl_xor(a.z, 16));
        a.w = fmaxf(a.w, __shfl_xor(a.w, 16));
        a.x = fmaxf(a.x, __shfl_xor(a.x, 32));
        a.y = fmaxf(a.y, __shfl_xor(a.y, 32));
        a.z = fmaxf(a.z, __shfl_xor(a.z, 32));
        a.w = fmaxf(a.w, __shfl_xor(a.w, 32));
        acc[jx] = a;
    }

    float* outr = out + (size_t)roi * (NBINS * CC) + c0;

    if (lane < 16) {
#pragma unroll
        for (int jx = 0; jx < 4; ++jx) {
            *(float4*)(outr + (size_t)(5 + jx * 4 + wv) * CC) = acc[jx];
            *(float4*)(&fineLds[wv][jx][cl * 4]) = acc[jx];
        }
    }
    __syncthreads();

    // p2: wave wv computes coarse bin (i2 = wv>>1, j2 = wv&1)
    {
        const int i2 = wv >> 1;
        const int j2 = wv & 1;
        if (lane < 16) {
            const float4 f00 = *(const float4*)(&fineLds[2*j2  ][2*i2  ][cl * 4]);
            const float4 f01 = *(const float4*)(&fineLds[2*j2  ][2*i2+1][cl * 4]);
            const float4 f10 = *(const float4*)(&fineLds[2*j2+1][2*i2  ][cl * 4]);
            const float4 f11 = *(const float4*)(&fineLds[2*j2+1][2*i2+1][cl * 4]);
            const float4 a = max4(max4(f00, f01), max4(f10, f11));
            *(float4*)(outr + (size_t)(1 + i2 * 2 + j2) * CC) = a;
            *(float4*)(&p2Lds[i2][j2][cl * 4]) = a;
        }
    }
    __syncthreads();

    // p1: wave 0
    if (wv == 0 && lane < 16) {
        const float4 a00 = *(const float4*)(&p2Lds[0][0][cl * 4]);
        const float4 a01 = *(const float4*)(&p2Lds[0][1][cl * 4]);
        const float4 a10 = *(const float4*)(&p2Lds[1][0][cl * 4]);
        const float4 a11 = *(const float4*)(&p2Lds[1][1][cl * 4]);
        *(float4*)(outr) = max4(max4(a00, a01), max4(a10, a11));
    }
}

extern "C" void kernel_launch(void* const* d_in, const int* in_sizes, int n_in,
                              void* d_out, int out_size, void* d_ws, size_t ws_size,
                              hipStream_t stream) {
    const float* img  = (const float*)d_in[0];   // (1,64,64,512) fp32
    const float* rois = (const float*)d_in[1];   // (1,256,4) fp32
    float* out = (float*)d_out;                  // (1,256,21*512) fp32

    dim3 grid(NROI * 8);     // (roi, eighth) = 2048 blocks
    dim3 block(256);
    roi_pool_fused<<<grid, block, 0, stream>>>(img, rois, out);
}

// Round 6
// 21.202 us; speedup vs baseline: 1.2105x; 1.2105x over previous
//
#include <hip/hip_runtime.h>
#include <math.h>

#define HF 64
#define WF 64
#define CC 512
#define NROI 256
#define NBINS 21   // 1 + 4 + 16

__device__ __forceinline__ float4 max4(float4 a, float4 b) {
    float4 r;
    r.x = fmaxf(a.x, b.x); r.y = fmaxf(a.y, b.y);
    r.z = fmaxf(a.z, b.z); r.w = fmaxf(a.w, b.w);
    return r;
}

// Fused kernel, round-3 wave structure preserved:
//   block = (roi, channel-quarter of 128 ch), 1024 threads = 16 waves.
//   wave wv -> fine bin (jy = wv>>2, jx = wv&3).
//   lanes: cl = lane&31 -> 4 channels (float4) over the 128-ch quarter,
//          half = lane>>5 -> 2-way pixel-column parity.
//   Inner loop = round-3 kernel A's loop + row-pair unroll (accA/accB,
//   2 independent outstanding loads per iteration).
//   p2/p1 derived block-locally via LDS (exact: fmax over identical operand
//   sets; boundary arithmetic bitwise-identical to reference).
// XCD swizzle (proven rounds 2-4): bid&7 -> XCD, quarter q = (bid&7)>>1 so
// quarter q lands on XCD pair {2q,2q+1}; per-XCD image slice 2 MB < 4 MiB L2.
__global__ __launch_bounds__(1024) void roi_pool_fused(
    const float* __restrict__ img,
    const float* __restrict__ rois,
    float* __restrict__ out)
{
    __shared__ float fineLds[4][4][128];   // [jy][jx][ch-in-quarter]
    __shared__ float p2Lds[2][2][128];     // [i2][j2][ch-in-quarter]

    const int bid  = blockIdx.x;                    // [0, 1024)
    const int q    = (bid & 7) >> 1;                // channel quarter
    const int roi  = ((bid >> 3) << 1) | (bid & 1); // [0, 256) bijective
    const int tid  = threadIdx.x;
    const int wv   = tid >> 6;                      // wave id = fine bin
    const int jy   = wv >> 2;                       // y fine-bin (H axis)
    const int jx   = wv & 3;                        // x fine-bin (W axis)
    const int lane = tid & 63;
    const int half = lane >> 5;                     // pixel-column parity
    const int cl   = lane & 31;                     // channel lane
    const int c0   = q * 128 + cl * 4;

    const float x = rois[roi * 4 + 0];
    const float y = rois[roi * 4 + 1];
    const float w = rois[roi * 4 + 2];
    const float h = rois[roi * 4 + 3];

    // Reference quirk: x-boundaries (W axis) use col_len = h/p; y-boundaries use w/p.
    const float clh = h * 0.25f;   // exact
    const float clw = w * 0.25f;   // exact

    const int x1 = (int)rintf(__fadd_rn(x, __fmul_rn((float)jx,       clh)));
    const int x2 = (int)rintf(__fadd_rn(x, __fmul_rn((float)(jx + 1), clh)));
    const int y1 = (int)rintf(__fadd_rn(y, __fmul_rn((float)jy,       clw)));
    const int y2 = (int)rintf(__fadd_rn(y, __fmul_rn((float)(jy + 1), clw)));

    float4 accA, accB;
    accA.x = -INFINITY; accA.y = -INFINITY; accA.z = -INFINITY; accA.w = -INFINITY;
    accB = accA;

    const float* base = img + c0;
    int hh = y1;
    // row-pair unroll: two independent accumulator chains -> 2 outstanding loads
    for (; hh + 1 < y2; hh += 2) {
        const float* r0 = base + (size_t)hh * (WF * CC);
        const float* r1 = r0 + (WF * CC);
        for (int ww0 = x1; ww0 < x2; ww0 += 2) {
            const int ww = ww0 + half;
            if (ww < x2) {
                const float4 v0 = *(const float4*)(r0 + (size_t)ww * CC);
                const float4 v1 = *(const float4*)(r1 + (size_t)ww * CC);
                accA = max4(accA, v0);
                accB = max4(accB, v1);
            }
        }
    }
    if (hh < y2) {   // tail row
        const float* r0 = base + (size_t)hh * (WF * CC);
        for (int ww0 = x1; ww0 < x2; ww0 += 2) {
            const int ww = ww0 + half;
            if (ww < x2) {
                accA = max4(accA, *(const float4*)(r0 + (size_t)ww * CC));
            }
        }
    }
    float4 acc = max4(accA, accB);

    // combine the two pixel-parity halves (same channels, disjoint pixel sets)
    acc.x = fmaxf(acc.x, __shfl_xor(acc.x, 32));
    acc.y = fmaxf(acc.y, __shfl_xor(acc.y, 32));
    acc.z = fmaxf(acc.z, __shfl_xor(acc.z, 32));
    acc.w = fmaxf(acc.w, __shfl_xor(acc.w, 32));

    float* outr = out + (size_t)roi * (NBINS * CC) + c0;

    if (half == 0) {
        *(float4*)(outr + (size_t)(5 + jx * 4 + jy) * CC) = acc;
        *(float4*)(&fineLds[jy][jx][cl * 4]) = acc;
    }
    __syncthreads();

    // p2: waves 0..3 -> coarse bin (i2 = wv>>1, j2 = wv&1), fine[ix][iy] = fineLds[iy][ix]
    if (wv < 4 && half == 0) {
        const int i2 = wv >> 1;
        const int j2 = wv & 1;
        const float4 f00 = *(const float4*)(&fineLds[2*j2  ][2*i2  ][cl * 4]);
        const float4 f01 = *(const float4*)(&fineLds[2*j2  ][2*i2+1][cl * 4]);
        const float4 f10 = *(const float4*)(&fineLds[2*j2+1][2*i2  ][cl * 4]);
        const float4 f11 = *(const float4*)(&fineLds[2*j2+1][2*i2+1][cl * 4]);
        const float4 a = max4(max4(f00, f01), max4(f10, f11));
        *(float4*)(outr + (size_t)(1 + i2 * 2 + j2) * CC) = a;
        *(float4*)(&p2Lds[i2][j2][cl * 4]) = a;
    }
    __syncthreads();

    // p1: wave 0
    if (wv == 0 && half == 0) {
        const float4 a00 = *(const float4*)(&p2Lds[0][0][cl * 4]);
        const float4 a01 = *(const float4*)(&p2Lds[0][1][cl * 4]);
        const float4 a10 = *(const float4*)(&p2Lds[1][0][cl * 4]);
        const float4 a11 = *(const float4*)(&p2Lds[1][1][cl * 4]);
        *(float4*)(outr) = max4(max4(a00, a01), max4(a10, a11));
    }
}

extern "C" void kernel_launch(void* const* d_in, const int* in_sizes, int n_in,
                              void* d_out, int out_size, void* d_ws, size_t ws_size,
                              hipStream_t stream) {
    const float* img  = (const float*)d_in[0];   // (1,64,64,512) fp32
    const float* rois = (const float*)d_in[1];   // (1,256,4) fp32
    float* out = (float*)d_out;                  // (1,256,21*512) fp32

    dim3 grid(NROI * 4);     // (roi, quarter) = 1024 blocks
    dim3 block(1024);        // 16 waves = 16 fine bins
    roi_pool_fused<<<grid, block, 0, stream>>>(img, rois, out);
}